// Round 6
// baseline (89.341 us; speedup 1.0000x reference)
//
#include <hip/hip_runtime.h>

#define B_SIZE 16384
#define K_NEG 20
#define DIM 128
#define NROWS 21                      // target + 20 negatives
#define NTASKS (B_SIZE * NROWS)       // 344064 row-dot tasks, = 5376 blocks * 64

// Fast stable log-sigmoid: logsig(x) = min(x,0) - log(1 + exp(-|x|)).
__device__ __forceinline__ float logsig(float x) {
    return fminf(x, 0.0f) - __logf(1.0f + __expf(-fabsf(x)));
}

// Task-per-quad layout: each (element,row) dot is owned by 4 lanes, each lane
// loading 32 contiguous floats (8 independent float4 gathers). 16 loads/lane
// in flight behind a hard sched fence -> ~16 KB outstanding per wave, no
// cross-lane shuffles in the dot inner loop.
__global__ __launch_bounds__(256, 4) void skipgram_loss_kernel(
    const int* __restrict__ center,
    const int* __restrict__ target,
    const int* __restrict__ neg,
    const float* __restrict__ V,
    const float* __restrict__ U,
    float* __restrict__ accum)
{
    const int tid  = threadIdx.x;
    const int lane = tid & 63;
    const int wid  = tid >> 6;
    const int seg  = lane & 3;                       // quarter-row [0,4)
    const int task = (blockIdx.x * 4 + wid) * 16 + (lane >> 2);

    const int e = task / NROWS;                      // magic-mul division
    const int r = task - e * NROWS;

    const int row = (r == 0) ? target[e] : neg[e * K_NEG + (r - 1)];
    const int ctr = center[e];

    const float4* up = (const float4*)(U + (size_t)row * DIM) + seg * 8;
    const float4* vp = (const float4*)(V + (size_t)ctr * DIM) + seg * 8;

    // Issue all 16 independent loads, then fence so the scheduler cannot
    // interleave consumers (R3/R4 lesson: without this, RA re-serializes).
    float4 u[8], v[8];
    #pragma unroll
    for (int j = 0; j < 8; ++j) u[j] = up[j];
    #pragma unroll
    for (int j = 0; j < 8; ++j) v[j] = vp[j];
    __builtin_amdgcn_sched_barrier(0);

    float d = 0.0f;
    #pragma unroll
    for (int j = 0; j < 8; ++j)
        d += u[j].x * v[j].x + u[j].y * v[j].y + u[j].z * v[j].z + u[j].w * v[j].w;

    // Sum the 4 quarter-dots within the quad (xor 1,2 stay inside the quad).
    d += __shfl_xor(d, 1, 64);
    d += __shfl_xor(d, 2, 64);

    // One lane per quad contributes the loss term.
    float term = (seg == 0) ? logsig(r == 0 ? d : -d) : 0.0f;

    // Butterfly over quads (masks 4..32 never mix lanes within a quad):
    // every lane ends with the sum over its seg-class; seg!=0 classes are 0.
    #pragma unroll
    for (int s = 4; s < 64; s <<= 1)
        term += __shfl_xor(term, s, 64);

    __shared__ float ssum[4];
    if (lane == 0) ssum[wid] = term;
    __syncthreads();
    if (tid == 0)
        atomicAdd(accum, ssum[0] + ssum[1] + ssum[2] + ssum[3]);
}

__global__ void finalize_kernel(const float* __restrict__ accum,
                                float* __restrict__ out)
{
    out[0] = -accum[0] * (1.0f / (float)B_SIZE);
}

extern "C" void kernel_launch(void* const* d_in, const int* in_sizes, int n_in,
                              void* d_out, int out_size, void* d_ws, size_t ws_size,
                              hipStream_t stream) {
    const int*   center = (const int*)d_in[0];
    const int*   target = (const int*)d_in[1];
    const int*   neg    = (const int*)d_in[2];
    const float* V      = (const float*)d_in[3];
    const float* U      = (const float*)d_in[4];
    float* out   = (float*)d_out;
    float* accum = (float*)d_ws;

    hipMemsetAsync(accum, 0, sizeof(float), stream);

    // 64 tasks per 256-thread block; NTASKS/64 = 5376 blocks, no tail.
    skipgram_loss_kernel<<<NTASKS / 64, 256, 0, stream>>>(center, target, neg, V, U, accum);
    finalize_kernel<<<1, 1, 0, stream>>>(accum, out);
}

// Round 8
// 41.838 us; speedup vs baseline: 2.1354x; 2.1354x over previous
//
#include <hip/hip_runtime.h>

#define B_SIZE 16384
#define K_NEG 20
#define DIM 128
#define NROWS 21            // target + 20 negatives
#define CHUNK 7             // rows per fused asm group (14 dwordx4 in flight)

// Fast stable log-sigmoid: logsig(x) = min(x,0) - log(1 + exp(-|x|)).
__device__ __forceinline__ float logsig(float x) {
    return fminf(x, 0.0f) - __logf(1.0f + __expf(-fabsf(x)));
}

__device__ __forceinline__ float dot8(float4 a0, float4 a1, float4 b0, float4 b1) {
    return a0.x * b0.x + a0.y * b0.y + a0.z * b0.z + a0.w * b0.w
         + a1.x * b1.x + a1.y * b1.y + a1.z * b1.z + a1.w * b1.w;
}

// R4 structure (4 elements/wave, 16 lanes x 32 B per row), but the 14 row
// gathers of each chunk are fused into a SINGLE asm block that also contains
// the vmcnt drain. R7 lesson: separate asm loads + separate waitcnt lets the
// RA insert copies/spills of in-flight dests between them (SIInsertWaitcnts
// can't see VMEM ops inside asm) -> garbage. One block = nothing can
// interleave; outputs are defined only after the internal s_waitcnt.
// "=&v" early-clobber keeps dests disjoint from the 7 address inputs.
__global__ __launch_bounds__(256, 4) void skipgram_loss_kernel(
    const int* __restrict__ center,
    const int* __restrict__ target,
    const int* __restrict__ neg,
    const float* __restrict__ V,
    const float* __restrict__ U,
    float* __restrict__ accum)
{
    const int tid  = threadIdx.x;
    const int lane = tid & 63;
    const int wid  = tid >> 6;
    const int sub  = lane >> 4;      // element within the wave [0,4)
    const int sl   = lane & 15;      // slot within the 128-float row

    const int e = blockIdx.x * 16 + wid * 4 + sub;   // batch element

    // All row indices up front (breaks idx->gather dependency chains).
    int idx[NROWS];
    idx[0] = target[e];
    {
        const int* nb = neg + e * K_NEG;
        #pragma unroll
        for (int k = 0; k < K_NEG; ++k) idx[k + 1] = nb[k];
    }

    // center embedding (V row): compiler-managed loads.
    const float4* vrow = (const float4*)(V + (size_t)center[e] * DIM);
    const float4 c0 = vrow[sl * 2];
    const float4 c1 = vrow[sl * 2 + 1];

    float acc = 0.0f;
    #pragma unroll
    for (int ch = 0; ch < 3; ++ch) {            // 21 rows = 3 chunks x 7
        const float4* p0 = (const float4*)(U + (size_t)idx[ch * CHUNK + 0] * DIM) + sl * 2;
        const float4* p1 = (const float4*)(U + (size_t)idx[ch * CHUNK + 1] * DIM) + sl * 2;
        const float4* p2 = (const float4*)(U + (size_t)idx[ch * CHUNK + 2] * DIM) + sl * 2;
        const float4* p3 = (const float4*)(U + (size_t)idx[ch * CHUNK + 3] * DIM) + sl * 2;
        const float4* p4 = (const float4*)(U + (size_t)idx[ch * CHUNK + 4] * DIM) + sl * 2;
        const float4* p5 = (const float4*)(U + (size_t)idx[ch * CHUNK + 5] * DIM) + sl * 2;
        const float4* p6 = (const float4*)(U + (size_t)idx[ch * CHUNK + 6] * DIM) + sl * 2;

        float4 a0[CHUNK], a1[CHUNK];
        asm volatile(
            "global_load_dwordx4 %0, %14, off\n\t"
            "global_load_dwordx4 %1, %14, off offset:16\n\t"
            "global_load_dwordx4 %2, %15, off\n\t"
            "global_load_dwordx4 %3, %15, off offset:16\n\t"
            "global_load_dwordx4 %4, %16, off\n\t"
            "global_load_dwordx4 %5, %16, off offset:16\n\t"
            "global_load_dwordx4 %6, %17, off\n\t"
            "global_load_dwordx4 %7, %17, off offset:16\n\t"
            "global_load_dwordx4 %8, %18, off\n\t"
            "global_load_dwordx4 %9, %18, off offset:16\n\t"
            "global_load_dwordx4 %10, %19, off\n\t"
            "global_load_dwordx4 %11, %19, off offset:16\n\t"
            "global_load_dwordx4 %12, %20, off\n\t"
            "global_load_dwordx4 %13, %20, off offset:16\n\t"
            "s_waitcnt vmcnt(0)"
            : "=&v"(a0[0]), "=&v"(a1[0]),
              "=&v"(a0[1]), "=&v"(a1[1]),
              "=&v"(a0[2]), "=&v"(a1[2]),
              "=&v"(a0[3]), "=&v"(a1[3]),
              "=&v"(a0[4]), "=&v"(a1[4]),
              "=&v"(a0[5]), "=&v"(a1[5]),
              "=&v"(a0[6]), "=&v"(a1[6])
            : "v"(p0), "v"(p1), "v"(p2), "v"(p3), "v"(p4), "v"(p5), "v"(p6)
            : "memory");

        float part[CHUNK];
        #pragma unroll
        for (int r = 0; r < CHUNK; ++r)
            part[r] = dot8(c0, c1, a0[r], a1[r]);

        // 4-step butterfly within each 16-lane group for this chunk.
        #pragma unroll
        for (int s = 1; s < 16; s <<= 1) {
            #pragma unroll
            for (int r = 0; r < CHUNK; ++r)
                part[r] += __shfl_xor(part[r], s, 64);
        }

        #pragma unroll
        for (int r = 0; r < CHUNK; ++r)
            acc += logsig((ch == 0 && r == 0) ? part[r] : -part[r]);
    }

    // Wave total: group leaders contribute, 2 more butterfly steps.
    float v = (sl == 0) ? acc : 0.0f;
    v += __shfl_xor(v, 16, 64);
    v += __shfl_xor(v, 32, 64);

    __shared__ float ssum[4];
    if (lane == 0) ssum[wid] = v;
    __syncthreads();
    if (tid == 0)
        atomicAdd(accum, ssum[0] + ssum[1] + ssum[2] + ssum[3]);
}

__global__ void finalize_kernel(const float* __restrict__ accum,
                                float* __restrict__ out)
{
    out[0] = -accum[0] * (1.0f / (float)B_SIZE);
}

extern "C" void kernel_launch(void* const* d_in, const int* in_sizes, int n_in,
                              void* d_out, int out_size, void* d_ws, size_t ws_size,
                              hipStream_t stream) {
    const int*   center = (const int*)d_in[0];
    const int*   target = (const int*)d_in[1];
    const int*   neg    = (const int*)d_in[2];
    const float* V      = (const float*)d_in[3];
    const float* U      = (const float*)d_in[4];
    float* out   = (float*)d_out;
    float* accum = (float*)d_ws;

    hipMemsetAsync(accum, 0, sizeof(float), stream);

    skipgram_loss_kernel<<<B_SIZE / 16, 256, 0, stream>>>(center, target, neg, V, U, accum);
    finalize_kernel<<<1, 1, 0, stream>>>(accum, out);
}